// Round 2
// baseline (1674.026 us; speedup 1.0000x reference)
//
#include <hip/hip_runtime.h>
#include <math.h>
#include <stddef.h>

#define BB 4
#define LL 1024
#define DM 512
#define ED 1024
#define NST 16
#define DTR 32
#define XDBC 64
#define BL (BB*LL)   // 4096

__device__ __forceinline__ float silu_f(float x) { return x / (1.f + __expf(-x)); }

// ---------------- embedding: h[m,d] = x[m,0]*W[d,0] + x[m,1]*W[d,1] + b[d]
__global__ void k_embed(const float* __restrict__ x, const float* __restrict__ W,
                        const float* __restrict__ bias, float* __restrict__ h) {
    int i = blockIdx.x * 256 + threadIdx.x;
    if (i >= BL * DM) return;
    int d = i % DM, r = i / DM;
    h[i] = x[r * 2 + 0] * W[d * 2 + 0] + x[r * 2 + 1] * W[d * 2 + 1] + bias[d];
}

// ---------------- rmsnorm over rows of 512
__global__ __launch_bounds__(256) void k_rmsnorm(const float* __restrict__ in,
                                                 const float* __restrict__ w,
                                                 float* __restrict__ out) {
    int m = blockIdx.x;
    int tid = threadIdx.x;
    const float* row = in + (size_t)m * DM;
    float2 v = *(const float2*)(row + tid * 2);
    float ss = v.x * v.x + v.y * v.y;
    #pragma unroll
    for (int o = 32; o > 0; o >>= 1) ss += __shfl_down(ss, o, 64);
    __shared__ float red[4];
    int wid = tid >> 6;
    if ((tid & 63) == 0) red[wid] = ss;
    __syncthreads();
    float tot = red[0] + red[1] + red[2] + red[3];
    float rs = rsqrtf(tot * (1.f / DM) + 1e-5f);
    float2 wv = *(const float2*)(w + tid * 2);
    float2 o2;
    o2.x = v.x * rs * wv.x;
    o2.y = v.y * rs * wv.y;
    *(float2*)(out + (size_t)m * DM + tid * 2) = o2;
}

// ---------------- 128x128 tiled fp32 GEMM: C[m,n] = (ADD?Res:0) + sum_k A[m,k]*W[n,k]
// A: M x K (lda), W: N x K (row-major, stride K), C: M x N (ldc)
template <int ADDRES>
__global__ __launch_bounds__(256) void k_gemm128(const float* __restrict__ A,
                                                 const float* __restrict__ W,
                                                 const float* __restrict__ Res,
                                                 float* __restrict__ C,
                                                 int M, int N, int K, int lda, int ldc) {
    __shared__ float As[8][128];
    __shared__ float Ws[8][128];
    int tid = threadIdx.x;
    int bm = blockIdx.y * 128, bn = blockIdx.x * 128;
    int arow = tid >> 1;         // 0..127
    int ak = (tid & 1) * 4;      // 0 or 4
    int tm = (tid >> 4) * 8;     // 0..120
    int tn = (tid & 15) * 8;
    float acc[8][8] = {};
    const float* Aptr = A + (size_t)(bm + arow) * lda + ak;
    const float* Wptr = W + (size_t)(bn + arow) * K + ak;
    for (int k0 = 0; k0 < K; k0 += 8) {
        float4 av = *(const float4*)(Aptr + k0);
        float4 wv = *(const float4*)(Wptr + k0);
        __syncthreads();
        As[ak + 0][arow] = av.x; As[ak + 1][arow] = av.y;
        As[ak + 2][arow] = av.z; As[ak + 3][arow] = av.w;
        Ws[ak + 0][arow] = wv.x; Ws[ak + 1][arow] = wv.y;
        Ws[ak + 2][arow] = wv.z; Ws[ak + 3][arow] = wv.w;
        __syncthreads();
        #pragma unroll
        for (int k = 0; k < 8; ++k) {
            float4 a0 = *(const float4*)&As[k][tm];
            float4 a1 = *(const float4*)&As[k][tm + 4];
            float4 b0 = *(const float4*)&Ws[k][tn];
            float4 b1 = *(const float4*)&Ws[k][tn + 4];
            float a[8] = {a0.x, a0.y, a0.z, a0.w, a1.x, a1.y, a1.z, a1.w};
            float b[8] = {b0.x, b0.y, b0.z, b0.w, b1.x, b1.y, b1.z, b1.w};
            #pragma unroll
            for (int i = 0; i < 8; ++i)
                #pragma unroll
                for (int j = 0; j < 8; ++j) acc[i][j] += a[i] * b[j];
        }
    }
    #pragma unroll
    for (int i = 0; i < 8; ++i) {
        size_t off = (size_t)(bm + tm + i) * ldc + bn + tn;
        float4 c0 = make_float4(acc[i][0], acc[i][1], acc[i][2], acc[i][3]);
        float4 c1 = make_float4(acc[i][4], acc[i][5], acc[i][6], acc[i][7]);
        if (ADDRES) {
            float4 r0 = *(const float4*)(Res + off);
            float4 r1 = *(const float4*)(Res + off + 4);
            c0.x += r0.x; c0.y += r0.y; c0.z += r0.z; c0.w += r0.w;
            c1.x += r1.x; c1.y += r1.y; c1.z += r1.z; c1.w += r1.w;
        }
        *(float4*)(C + off) = c0;
        *(float4*)(C + off + 4) = c1;
    }
}

// ---------------- 64x64 tiled fp32 GEMM (for x_proj, N=64)
__global__ __launch_bounds__(256) void k_gemm64(const float* __restrict__ A,
                                                const float* __restrict__ W,
                                                float* __restrict__ C,
                                                int M, int N, int K, int lda, int ldc) {
    __shared__ float As[16][64];
    __shared__ float Ws[16][64];
    int tid = threadIdx.x;
    int bm = blockIdx.y * 64, bn = blockIdx.x * 64;
    int lrow = tid >> 2;         // 0..63
    int lk = (tid & 3) * 4;      // 0,4,8,12
    int tm = (tid >> 4) * 4;
    int tn = (tid & 15) * 4;
    float acc[4][4] = {};
    for (int k0 = 0; k0 < K; k0 += 16) {
        float4 av = *(const float4*)(A + (size_t)(bm + lrow) * lda + k0 + lk);
        float4 wv = *(const float4*)(W + (size_t)(bn + lrow) * K + k0 + lk);
        __syncthreads();
        As[lk + 0][lrow] = av.x; As[lk + 1][lrow] = av.y;
        As[lk + 2][lrow] = av.z; As[lk + 3][lrow] = av.w;
        Ws[lk + 0][lrow] = wv.x; Ws[lk + 1][lrow] = wv.y;
        Ws[lk + 2][lrow] = wv.z; Ws[lk + 3][lrow] = wv.w;
        __syncthreads();
        #pragma unroll
        for (int k = 0; k < 16; ++k) {
            float4 a = *(const float4*)&As[k][tm];
            float4 b = *(const float4*)&Ws[k][tn];
            acc[0][0] += a.x * b.x; acc[0][1] += a.x * b.y; acc[0][2] += a.x * b.z; acc[0][3] += a.x * b.w;
            acc[1][0] += a.y * b.x; acc[1][1] += a.y * b.y; acc[1][2] += a.y * b.z; acc[1][3] += a.y * b.w;
            acc[2][0] += a.z * b.x; acc[2][1] += a.z * b.y; acc[2][2] += a.z * b.z; acc[2][3] += a.z * b.w;
            acc[3][0] += a.w * b.x; acc[3][1] += a.w * b.y; acc[3][2] += a.w * b.z; acc[3][3] += a.w * b.w;
        }
    }
    #pragma unroll
    for (int i = 0; i < 4; ++i) {
        size_t off = (size_t)(bm + tm + i) * ldc + bn + tn;
        *(float4*)(C + off) = make_float4(acc[i][0], acc[i][1], acc[i][2], acc[i][3]);
    }
}

// ---------------- causal depthwise conv (k=4) + bias + silu
// xz: (BL, 2048) rows; u-part is cols [0,1024)
__global__ void k_conv(const float* __restrict__ xz, const float* __restrict__ cw,
                       const float* __restrict__ cb, float* __restrict__ u) {
    int i = blockIdx.x * 256 + threadIdx.x;
    if (i >= BL * ED) return;
    int e = i % ED;
    int t = (i / ED) % LL;
    int b = i / (ED * LL);
    const float* col = xz + (size_t)b * LL * 2048 + e;
    float4 w4 = *(const float4*)(cw + e * 4);
    float acc = cb[e];
    if (t >= 3) acc += col[(size_t)(t - 3) * 2048] * w4.x;
    if (t >= 2) acc += col[(size_t)(t - 2) * 2048] * w4.y;
    if (t >= 1) acc += col[(size_t)(t - 1) * 2048] * w4.z;
    acc += col[(size_t)t * 2048] * w4.w;
    u[i] = silu_f(acc);
}

// ---------------- delta = softplus(dt @ dtW^T + dtb); dt = xdb[:, :32]
__global__ __launch_bounds__(256) void k_delta(const float* __restrict__ xdb,
                                               const float* __restrict__ dtW,
                                               const float* __restrict__ dtb,
                                               float* __restrict__ delta) {
    int m = blockIdx.x;
    int tid = threadIdx.x;
    __shared__ float dt[32];
    if (tid < 32) dt[tid] = xdb[(size_t)m * XDBC + tid];
    __syncthreads();
    for (int e = tid; e < ED; e += 256) {
        const float4* wp = (const float4*)(dtW + (size_t)e * 32);
        float acc = dtb[e];
        #pragma unroll
        for (int q = 0; q < 8; ++q) {
            float4 w = wp[q];
            acc += dt[q * 4 + 0] * w.x + dt[q * 4 + 1] * w.y +
                   dt[q * 4 + 2] * w.z + dt[q * 4 + 3] * w.w;
        }
        delta[(size_t)m * ED + e] = (acc > 20.f) ? acc : __logf(1.f + __expf(acc));
    }
}

// ---------------- selective scan: 16 lanes = 16 states of one (b,e) channel.
// dy holds delta on entry, y on exit (in-place, read-before-write per t).
__global__ __launch_bounds__(256) void k_scan(float* __restrict__ dy,
                                              const float* __restrict__ u,
                                              const float* __restrict__ xdb,
                                              const float* __restrict__ A_log,
                                              const float* __restrict__ Dskip) {
    int tid = threadIdx.x;
    int n = tid & 15;
    int g = tid >> 4;                       // 0..15 groups per block
    int b = blockIdx.x >> 6;                // 4 batches
    int e = ((blockIdx.x & 63) << 4) + g;   // 0..1023
    float Ac = -__expf(A_log[e * NST + n]);
    float Dk = Dskip[e];
    const float* up = u + (size_t)b * LL * ED + e;
    float* dp = dy + (size_t)b * LL * ED + e;
    const float* xp = xdb + (size_t)b * LL * XDBC;
    float h = 0.f;
    for (int t = 0; t < LL; ++t) {
        float dv = dp[(size_t)t * ED];
        float uv = up[(size_t)t * ED];
        float Bv = xp[t * XDBC + DTR + n];
        float Cv = xp[t * XDBC + DTR + NST + n];
        h = __expf(dv * Ac) * h + dv * Bv * uv;
        float p = h * Cv;
        p += __shfl_xor(p, 1, 16);
        p += __shfl_xor(p, 2, 16);
        p += __shfl_xor(p, 4, 16);
        p += __shfl_xor(p, 8, 16);
        if (n == 0) dp[(size_t)t * ED] = p + Dk * uv;
    }
}

// ---------------- y *= silu(z); z = xz[:, 1024+e]
__global__ void k_gate(float* __restrict__ y, const float* __restrict__ xz) {
    int i = blockIdx.x * 256 + threadIdx.x;
    if (i >= BL * ED) return;
    int e = i % ED;
    int m = i / ED;
    float z = xz[(size_t)m * 2048 + 1024 + e];
    y[i] *= silu_f(z);
}

extern "C" void kernel_launch(void* const* d_in, const int* in_sizes, int n_in,
                              void* d_out, int out_size, void* d_ws, size_t ws_size,
                              hipStream_t stream) {
    const float* x     = (const float*)d_in[0];
    const float* embW  = (const float*)d_in[1];
    const float* embB  = (const float*)d_in[2];
    const float* normw = (const float*)d_in[3];
    const float* ipW   = (const float*)d_in[4];
    const float* cW    = (const float*)d_in[5];
    const float* cb    = (const float*)d_in[6];
    const float* xpW   = (const float*)d_in[7];
    const float* dtW   = (const float*)d_in[8];
    const float* dtb   = (const float*)d_in[9];
    const float* Alog  = (const float*)d_in[10];
    const float* Dsk   = (const float*)d_in[11];
    const float* opW   = (const float*)d_in[12];
    const float* normfw= (const float*)d_in[13];
    float* out = (float*)d_out;

    // workspace layout (floats): h(2M) xz(8M) u(4M) xdb(256K) dy(4M)  ~= 73 MB
    float* ws  = (float*)d_ws;
    float* h   = ws;
    float* xz  = h + (size_t)BL * DM;
    float* u   = xz + (size_t)BL * 2 * ED;
    float* xdb = u + (size_t)BL * ED;
    float* dy  = xdb + (size_t)BL * XDBC;
    float* hn  = out;  // reuse d_out as h_norm scratch (fully rewritten at the end)

    k_embed<<<(BL * DM + 255) / 256, 256, 0, stream>>>(x, embW, embB, h);
    for (int l = 0; l < 2; ++l) {
        k_rmsnorm<<<BL, 256, 0, stream>>>(h, normw + (size_t)l * DM, hn);
        k_gemm128<0><<<dim3(2 * ED / 128, BL / 128), 256, 0, stream>>>(
            hn, ipW + (size_t)l * 2 * ED * DM, nullptr, xz, BL, 2 * ED, DM, DM, 2 * ED);
        k_conv<<<(BL * ED + 255) / 256, 256, 0, stream>>>(
            xz, cW + (size_t)l * ED * 4, cb + (size_t)l * ED, u);
        k_gemm64<<<dim3(1, BL / 64), 256, 0, stream>>>(
            u, xpW + (size_t)l * XDBC * ED, xdb, BL, XDBC, ED, ED, XDBC);
        k_delta<<<BL, 256, 0, stream>>>(
            xdb, dtW + (size_t)l * ED * DTR, dtb + (size_t)l * ED, dy);
        k_scan<<<256, 256, 0, stream>>>(
            dy, u, xdb, Alog + (size_t)l * ED * NST, Dsk + (size_t)l * ED);
        k_gate<<<(BL * ED + 255) / 256, 256, 0, stream>>>(dy, xz);
        k_gemm128<1><<<dim3(DM / 128, BL / 128), 256, 0, stream>>>(
            dy, opW + (size_t)l * DM * ED, h, h, BL, DM, ED, ED, DM);
    }
    k_rmsnorm<<<BL, 256, 0, stream>>>(h, normfw, out);
}

// Round 5
// 502.483 us; speedup vs baseline: 3.3315x; 3.3315x over previous
//
#include <hip/hip_runtime.h>
#include <math.h>
#include <stddef.h>

#define BB 4
#define LL 1024
#define DM 512
#define ED 1024
#define NST 16
#define DTR 32
#define XDBC 64
#define BL (BB*LL)   // 4096
#define CS 32        // scan chunk length
#define NC 32        // chunks per sequence (LL/CS)
#define LDSK 40      // padded LDS k-stride (ushorts): 80B rows, 16B-aligned, 2-way max bank alias

typedef __attribute__((ext_vector_type(8))) short bf16x8;
typedef __attribute__((ext_vector_type(4))) float f32x4;
typedef unsigned short ushort_t;

__device__ __forceinline__ float silu_f(float x) { return x / (1.f + __expf(-x)); }

// fp32 -> bf16 round-to-nearest-even
__device__ __forceinline__ ushort_t f2b(float f) {
    unsigned int u = __float_as_uint(f);
    unsigned int r = (u + 0x7FFFu + ((u >> 16) & 1u)) >> 16;
    return (ushort_t)r;
}

// ---------------- embedding
__global__ void k_embed(const float* __restrict__ x, const float* __restrict__ W,
                        const float* __restrict__ bias, float* __restrict__ h) {
    int i = blockIdx.x * 256 + threadIdx.x;
    if (i >= BL * DM) return;
    int d = i % DM, r = i / DM;
    h[i] = x[r * 2 + 0] * W[d * 2 + 0] + x[r * 2 + 1] * W[d * 2 + 1] + bias[d];
}

// ---------------- fp32 -> bf16 bulk convert (n multiple of 4)
__global__ void k_cvt(const float* __restrict__ in, ushort_t* __restrict__ out, int n4) {
    int i = blockIdx.x * 256 + threadIdx.x;
    if (i >= n4) return;
    float4 v = *(const float4*)(in + (size_t)i * 4);
    ushort_t o[4] = {f2b(v.x), f2b(v.y), f2b(v.z), f2b(v.w)};
    *(uint2*)(out + (size_t)i * 4) = *(uint2*)o;
}

// ---------------- rmsnorm over rows of 512; BF16OUT selects output dtype
template <int BF16OUT>
__global__ __launch_bounds__(256) void k_rmsnorm(const float* __restrict__ in,
                                                 const float* __restrict__ w,
                                                 void* __restrict__ outp) {
    int m = blockIdx.x;
    int tid = threadIdx.x;
    const float* row = in + (size_t)m * DM;
    float2 v = *(const float2*)(row + tid * 2);
    float ss = v.x * v.x + v.y * v.y;
    #pragma unroll
    for (int o = 32; o > 0; o >>= 1) ss += __shfl_down(ss, o, 64);
    __shared__ float red[4];
    int wid = tid >> 6;
    if ((tid & 63) == 0) red[wid] = ss;
    __syncthreads();
    float tot = red[0] + red[1] + red[2] + red[3];
    float rs = rsqrtf(tot * (1.f / DM) + 1e-5f);
    float2 wv = *(const float2*)(w + tid * 2);
    float ox = v.x * rs * wv.x;
    float oy = v.y * rs * wv.y;
    if (BF16OUT) {
        ushort_t o[2] = {f2b(ox), f2b(oy)};
        *(unsigned int*)((ushort_t*)outp + (size_t)m * DM + tid * 2) = *(unsigned int*)o;
    } else {
        *(float2*)((float*)outp + (size_t)m * DM + tid * 2) = make_float2(ox, oy);
    }
}

// ---------------- bf16 MFMA GEMM: C[m,n] = (ADD?Res:0) + sum_k A[m,k]*W[n,k]
// A: M x K bf16 (lda), W: N x K bf16 (stride K), C/Res: fp32 (ldc).
// 128x128 tile, 4 waves as 2x2 of 64x64, BK=32, mfma_f32_16x16x32_bf16.
template <int ADDRES>
__global__ __launch_bounds__(256) void k_bgemm(const ushort_t* __restrict__ A,
                                               const ushort_t* __restrict__ W,
                                               const float* __restrict__ Res,
                                               float* __restrict__ C,
                                               int M, int N, int K, int lda, int ldc) {
    __shared__ ushort_t As[128 * LDSK];
    __shared__ ushort_t Bs[128 * LDSK];
    int tid = threadIdx.x;
    int bm = blockIdx.y * 128, bn = blockIdx.x * 128;
    int wave = tid >> 6, lane = tid & 63;
    int wr = wave >> 1, wc = wave & 1;       // 2x2 wave grid, 64x64 each
    int lr = lane & 15, lk = (lane >> 4) * 8;
    int srow = tid >> 2;                     // staging: 0..63
    int skb = (tid & 3) * 8;                 // k-chunk 0,8,16,24
    f32x4 acc[4][4];
    #pragma unroll
    for (int i = 0; i < 4; ++i)
        #pragma unroll
        for (int j = 0; j < 4; ++j) acc[i][j] = (f32x4){0.f, 0.f, 0.f, 0.f};

    for (int k0 = 0; k0 < K; k0 += 32) {
        uint4 a0 = *(const uint4*)(A + (size_t)(bm + srow) * lda + k0 + skb);
        uint4 a1 = *(const uint4*)(A + (size_t)(bm + 64 + srow) * lda + k0 + skb);
        uint4 b0 = *(const uint4*)(W + (size_t)(bn + srow) * K + k0 + skb);
        uint4 b1 = *(const uint4*)(W + (size_t)(bn + 64 + srow) * K + k0 + skb);
        __syncthreads();
        *(uint4*)(As + srow * LDSK + skb) = a0;
        *(uint4*)(As + (64 + srow) * LDSK + skb) = a1;
        *(uint4*)(Bs + srow * LDSK + skb) = b0;
        *(uint4*)(Bs + (64 + srow) * LDSK + skb) = b1;
        __syncthreads();
        bf16x8 af[4], bfr[4];
        #pragma unroll
        for (int i = 0; i < 4; ++i)
            af[i] = *(const bf16x8*)(As + (wr * 64 + i * 16 + lr) * LDSK + lk);
        #pragma unroll
        for (int j = 0; j < 4; ++j)
            bfr[j] = *(const bf16x8*)(Bs + (wc * 64 + j * 16 + lr) * LDSK + lk);
        #pragma unroll
        for (int i = 0; i < 4; ++i)
            #pragma unroll
            for (int j = 0; j < 4; ++j)
                acc[i][j] = __builtin_amdgcn_mfma_f32_16x16x32_bf16(af[i], bfr[j], acc[i][j], 0, 0, 0);
    }
    // C/D layout: col = lane&15, row = (lane>>4)*4 + reg  [m89-verified]
    int crow0 = bm + wr * 64 + (lane >> 4) * 4;
    int ccol0 = bn + wc * 64 + lr;
    #pragma unroll
    for (int i = 0; i < 4; ++i)
        #pragma unroll
        for (int j = 0; j < 4; ++j)
            #pragma unroll
            for (int r = 0; r < 4; ++r) {
                size_t off = (size_t)(crow0 + i * 16 + r) * ldc + ccol0 + j * 16;
                float v = acc[i][j][r];
                if (ADDRES) v += Res[off];
                C[off] = v;
            }
}

// ---------------- 64x64 tiled fp32 GEMM (x_proj, N=64)
__global__ __launch_bounds__(256) void k_gemm64(const float* __restrict__ A,
                                                const float* __restrict__ W,
                                                float* __restrict__ C,
                                                int M, int N, int K, int lda, int ldc) {
    __shared__ float As[16][64];
    __shared__ float Ws[16][64];
    int tid = threadIdx.x;
    int bm = blockIdx.y * 64, bn = blockIdx.x * 64;
    int lrow = tid >> 2;
    int lk = (tid & 3) * 4;
    int tm = (tid >> 4) * 4;
    int tn = (tid & 15) * 4;
    float acc[4][4] = {};
    for (int k0 = 0; k0 < K; k0 += 16) {
        float4 av = *(const float4*)(A + (size_t)(bm + lrow) * lda + k0 + lk);
        float4 wv = *(const float4*)(W + (size_t)(bn + lrow) * K + k0 + lk);
        __syncthreads();
        As[lk + 0][lrow] = av.x; As[lk + 1][lrow] = av.y;
        As[lk + 2][lrow] = av.z; As[lk + 3][lrow] = av.w;
        Ws[lk + 0][lrow] = wv.x; Ws[lk + 1][lrow] = wv.y;
        Ws[lk + 2][lrow] = wv.z; Ws[lk + 3][lrow] = wv.w;
        __syncthreads();
        #pragma unroll
        for (int k = 0; k < 16; ++k) {
            float4 a = *(const float4*)&As[k][tm];
            float4 b = *(const float4*)&Ws[k][tn];
            acc[0][0] += a.x * b.x; acc[0][1] += a.x * b.y; acc[0][2] += a.x * b.z; acc[0][3] += a.x * b.w;
            acc[1][0] += a.y * b.x; acc[1][1] += a.y * b.y; acc[1][2] += a.y * b.z; acc[1][3] += a.y * b.w;
            acc[2][0] += a.z * b.x; acc[2][1] += a.z * b.y; acc[2][2] += a.z * b.z; acc[2][3] += a.z * b.w;
            acc[3][0] += a.w * b.x; acc[3][1] += a.w * b.y; acc[3][2] += a.w * b.z; acc[3][3] += a.w * b.w;
        }
    }
    #pragma unroll
    for (int i = 0; i < 4; ++i) {
        size_t off = (size_t)(bm + tm + i) * ldc + bn + tn;
        *(float4*)(C + off) = make_float4(acc[i][0], acc[i][1], acc[i][2], acc[i][3]);
    }
}

// ---------------- causal depthwise conv (k=4) + bias + silu
__global__ void k_conv(const float* __restrict__ xz, const float* __restrict__ cw,
                       const float* __restrict__ cb, float* __restrict__ u) {
    int i = blockIdx.x * 256 + threadIdx.x;
    if (i >= BL * ED) return;
    int e = i % ED;
    int t = (i / ED) % LL;
    int b = i / (ED * LL);
    const float* col = xz + (size_t)b * LL * 2048 + e;
    float4 w4 = *(const float4*)(cw + e * 4);
    float acc = cb[e];
    if (t >= 3) acc += col[(size_t)(t - 3) * 2048] * w4.x;
    if (t >= 2) acc += col[(size_t)(t - 2) * 2048] * w4.y;
    if (t >= 1) acc += col[(size_t)(t - 1) * 2048] * w4.z;
    acc += col[(size_t)t * 2048] * w4.w;
    u[i] = silu_f(acc);
}

// ---------------- delta = softplus(dt @ dtW^T + dtb)
__global__ __launch_bounds__(256) void k_delta(const float* __restrict__ xdb,
                                               const float* __restrict__ dtW,
                                               const float* __restrict__ dtb,
                                               float* __restrict__ delta) {
    int m = blockIdx.x;
    int tid = threadIdx.x;
    __shared__ float dt[32];
    if (tid < 32) dt[tid] = xdb[(size_t)m * XDBC + tid];
    __syncthreads();
    for (int e = tid; e < ED; e += 256) {
        const float4* wp = (const float4*)(dtW + (size_t)e * 32);
        float acc = dtb[e];
        #pragma unroll
        for (int q = 0; q < 8; ++q) {
            float4 w = wp[q];
            acc += dt[q * 4 + 0] * w.x + dt[q * 4 + 1] * w.y +
                   dt[q * 4 + 2] * w.z + dt[q * 4 + 3] * w.w;
        }
        delta[(size_t)m * ED + e] = (acc > 20.f) ? acc : __logf(1.f + __expf(acc));
    }
}

// ================ chunked selective scan ================
__global__ __launch_bounds__(256) void k_scan1(const float* __restrict__ delta,
                                               const float* __restrict__ u,
                                               const float* __restrict__ xdb,
                                               const float* __restrict__ A_log,
                                               float* __restrict__ P,
                                               float* __restrict__ S) {
    int tid = threadIdx.x;
    int e = ((blockIdx.x & 3) << 8) + tid;
    int c = (blockIdx.x >> 2) & (NC - 1);
    int b = blockIdx.x >> 7;
    float Ac[16];
    const float4* ap = (const float4*)(A_log + (size_t)e * NST);
    #pragma unroll
    for (int q = 0; q < 4; ++q) {
        float4 a = ap[q];
        Ac[q * 4 + 0] = -__expf(a.x); Ac[q * 4 + 1] = -__expf(a.y);
        Ac[q * 4 + 2] = -__expf(a.z); Ac[q * 4 + 3] = -__expf(a.w);
    }
    float h[16] = {};
    float s = 0.f;
    const float* dp = delta + ((size_t)b * LL + c * CS) * ED + e;
    const float* up = u + ((size_t)b * LL + c * CS) * ED + e;
    const float* xp = xdb + ((size_t)b * LL + c * CS) * XDBC;
    for (int tt = 0; tt < CS; ++tt) {
        float dv = dp[(size_t)tt * ED];
        float uv = up[(size_t)tt * ED];
        s += dv;
        float du = dv * uv;
        const float4* bp = (const float4*)(xp + tt * XDBC + DTR);
        #pragma unroll
        for (int q = 0; q < 4; ++q) {
            float4 bv = bp[q];
            h[q * 4 + 0] = __expf(dv * Ac[q * 4 + 0]) * h[q * 4 + 0] + du * bv.x;
            h[q * 4 + 1] = __expf(dv * Ac[q * 4 + 1]) * h[q * 4 + 1] + du * bv.y;
            h[q * 4 + 2] = __expf(dv * Ac[q * 4 + 2]) * h[q * 4 + 2] + du * bv.z;
            h[q * 4 + 3] = __expf(dv * Ac[q * 4 + 3]) * h[q * 4 + 3] + du * bv.w;
        }
    }
    float4* pp = (float4*)(P + ((size_t)(b * NC + c) * ED + e) * NST);
    pp[0] = make_float4(h[0], h[1], h[2], h[3]);
    pp[1] = make_float4(h[4], h[5], h[6], h[7]);
    pp[2] = make_float4(h[8], h[9], h[10], h[11]);
    pp[3] = make_float4(h[12], h[13], h[14], h[15]);
    S[(size_t)(b * NC + c) * ED + e] = s;
}

__global__ __launch_bounds__(256) void k_scan2(float* __restrict__ P,
                                               const float* __restrict__ S,
                                               const float* __restrict__ A_log) {
    int i = blockIdx.x * 256 + threadIdx.x;
    int n = i & 15;
    int e = (i >> 4) & (ED - 1);
    int b = i >> 14;
    float Ac = -__expf(A_log[(size_t)e * NST + n]);
    float hin = 0.f;
    for (int c = 0; c < NC; ++c) {
        size_t base = (size_t)(b * NC + c) * ED + e;
        float p = P[base * NST + n];
        float s = S[base];
        P[base * NST + n] = hin;
        hin = __expf(Ac * s) * hin + p;
    }
}

// Pass 3: re-scan with correct h_in; y = sum_n h*C + D*u, fused silu(z) gate;
// emits bf16 yb for the out_proj MFMA GEMM.
__global__ __launch_bounds__(256) void k_scan3(const float* __restrict__ dy,
                                               const float* __restrict__ u,
                                               const float* __restrict__ xdb,
                                               const float* __restrict__ xz,
                                               const float* __restrict__ A_log,
                                               const float* __restrict__ Dskip,
                                               const float* __restrict__ P,
                                               ushort_t* __restrict__ yb) {
    int tid = threadIdx.x;
    int e = ((blockIdx.x & 3) << 8) + tid;
    int c = (blockIdx.x >> 2) & (NC - 1);
    int b = blockIdx.x >> 7;
    float Ac[16], h[16];
    const float4* ap = (const float4*)(A_log + (size_t)e * NST);
    #pragma unroll
    for (int q = 0; q < 4; ++q) {
        float4 a = ap[q];
        Ac[q * 4 + 0] = -__expf(a.x); Ac[q * 4 + 1] = -__expf(a.y);
        Ac[q * 4 + 2] = -__expf(a.z); Ac[q * 4 + 3] = -__expf(a.w);
    }
    const float4* pp = (const float4*)(P + ((size_t)(b * NC + c) * ED + e) * NST);
    #pragma unroll
    for (int q = 0; q < 4; ++q) {
        float4 hv = pp[q];
        h[q * 4 + 0] = hv.x; h[q * 4 + 1] = hv.y;
        h[q * 4 + 2] = hv.z; h[q * 4 + 3] = hv.w;
    }
    float Dk = Dskip[e];
    const float* dp = dy + ((size_t)b * LL + c * CS) * ED + e;
    const float* up = u + ((size_t)b * LL + c * CS) * ED + e;
    const float* xp = xdb + ((size_t)b * LL + c * CS) * XDBC;
    const float* zp = xz + ((size_t)b * LL + c * CS) * 2048 + 1024 + e;
    ushort_t* yp = yb + ((size_t)b * LL + c * CS) * ED + e;
    for (int tt = 0; tt < CS; ++tt) {
        float dv = dp[(size_t)tt * ED];
        float uv = up[(size_t)tt * ED];
        float zv = zp[(size_t)tt * 2048];
        float du = dv * uv;
        const float4* bp = (const float4*)(xp + tt * XDBC + DTR);
        const float4* cp = (const float4*)(xp + tt * XDBC + DTR + NST);
        float y = 0.f;
        #pragma unroll
        for (int q = 0; q < 4; ++q) {
            float4 bv = bp[q];
            float4 cv = cp[q];
            h[q * 4 + 0] = __expf(dv * Ac[q * 4 + 0]) * h[q * 4 + 0] + du * bv.x;
            h[q * 4 + 1] = __expf(dv * Ac[q * 4 + 1]) * h[q * 4 + 1] + du * bv.y;
            h[q * 4 + 2] = __expf(dv * Ac[q * 4 + 2]) * h[q * 4 + 2] + du * bv.z;
            h[q * 4 + 3] = __expf(dv * Ac[q * 4 + 3]) * h[q * 4 + 3] + du * bv.w;
            y += h[q * 4 + 0] * cv.x + h[q * 4 + 1] * cv.y +
                 h[q * 4 + 2] * cv.z + h[q * 4 + 3] * cv.w;
        }
        yp[(size_t)tt * ED] = f2b((y + Dk * uv) * silu_f(zv));
    }
}

extern "C" void kernel_launch(void* const* d_in, const int* in_sizes, int n_in,
                              void* d_out, int out_size, void* d_ws, size_t ws_size,
                              hipStream_t stream) {
    const float* x     = (const float*)d_in[0];
    const float* embW  = (const float*)d_in[1];
    const float* embB  = (const float*)d_in[2];
    const float* normw = (const float*)d_in[3];
    const float* ipW   = (const float*)d_in[4];
    const float* cW    = (const float*)d_in[5];
    const float* cb    = (const float*)d_in[6];
    const float* xpW   = (const float*)d_in[7];
    const float* dtW   = (const float*)d_in[8];
    const float* dtb   = (const float*)d_in[9];
    const float* Alog  = (const float*)d_in[10];
    const float* Dsk   = (const float*)d_in[11];
    const float* opW   = (const float*)d_in[12];
    const float* normfw= (const float*)d_in[13];
    float* out = (float*)d_out;

    // ws (floats): h 2M | xz 8M | u 4M | xdb 256K | dy 4M | S 128K, then
    // ushorts: wb 2.5M (per-layer bf16 weights) | yb 4M  => ~87 MB total
    float* ws  = (float*)d_ws;
    float* h   = ws;
    float* xz  = h + (size_t)BL * DM;
    float* u   = xz + (size_t)BL * 2 * ED;
    float* xdb = u + (size_t)BL * ED;
    float* dy  = xdb + (size_t)BL * XDBC;
    float* S   = dy + (size_t)BL * ED;
    ushort_t* wip = (ushort_t*)(S + (size_t)BB * NC * ED);  // 2*ED*DM bf16
    ushort_t* wop = wip + (size_t)2 * ED * DM;              // DM*ED bf16
    ushort_t* yb  = wop + (size_t)DM * ED;                  // BL*ED bf16
    ushort_t* hnb = (ushort_t*)d_out;  // bf16 rmsnorm scratch (d_out reuse)
    float* P      = out;               // chunk-state buffer (d_out reuse)

    k_embed<<<(BL * DM + 255) / 256, 256, 0, stream>>>(x, embW, embB, h);
    for (int l = 0; l < 2; ++l) {
        k_cvt<<<(2 * ED * DM / 4 + 255) / 256, 256, 0, stream>>>(
            ipW + (size_t)l * 2 * ED * DM, wip, 2 * ED * DM / 4);
        k_cvt<<<(DM * ED / 4 + 255) / 256, 256, 0, stream>>>(
            opW + (size_t)l * DM * ED, wop, DM * ED / 4);
        k_rmsnorm<1><<<BL, 256, 0, stream>>>(h, normw + (size_t)l * DM, hnb);
        k_bgemm<0><<<dim3(2 * ED / 128, BL / 128), 256, 0, stream>>>(
            hnb, wip, nullptr, xz, BL, 2 * ED, DM, DM, 2 * ED);
        k_conv<<<(BL * ED + 255) / 256, 256, 0, stream>>>(
            xz, cW + (size_t)l * ED * 4, cb + (size_t)l * ED, u);
        k_gemm64<<<dim3(1, BL / 64), 256, 0, stream>>>(
            u, xpW + (size_t)l * XDBC * ED, xdb, BL, XDBC, ED, ED, XDBC);
        k_delta<<<BL, 256, 0, stream>>>(
            xdb, dtW + (size_t)l * ED * DTR, dtb + (size_t)l * ED, dy);
        const float* Al = Alog + (size_t)l * ED * NST;
        k_scan1<<<BB * NC * (ED / 256), 256, 0, stream>>>(dy, u, xdb, Al, P, S);
        k_scan2<<<BB * ED * NST / 256, 256, 0, stream>>>(P, S, Al);
        k_scan3<<<BB * NC * (ED / 256), 256, 0, stream>>>(
            dy, u, xdb, xz, Al, Dsk + (size_t)l * ED, P, yb);
        k_bgemm<1><<<dim3(DM / 128, BL / 128), 256, 0, stream>>>(
            yb, wop, h, h, BL, DM, ED, ED, DM);
    }
    k_rmsnorm<0><<<BL, 256, 0, stream>>>(h, normfw, out);
}

// Round 6
// 408.338 us; speedup vs baseline: 4.0996x; 1.2306x over previous
//
#include <hip/hip_runtime.h>
#include <math.h>
#include <stddef.h>

#define BB 4
#define LL 1024
#define DM 512
#define ED 1024
#define NST 16
#define DTR 32
#define XDBC 64
#define BL (BB*LL)   // 4096
#define CS 32        // scan chunk length
#define NC 32        // chunks per sequence (LL/CS)
#define LDSK 40      // padded LDS k-stride (ushorts) for bf16 GEMM
#define XKS 16       // x_proj K-slices
#define XPAD 68      // x_proj LDS stride (floats): 272B, 16B-aligned

typedef __attribute__((ext_vector_type(8))) short bf16x8;
typedef __attribute__((ext_vector_type(4))) float f32x4;
typedef unsigned short ushort_t;

__device__ __forceinline__ float silu_f(float x) { return x / (1.f + __expf(-x)); }

// fp32 -> bf16 round-to-nearest-even
__device__ __forceinline__ ushort_t f2b(float f) {
    unsigned int u = __float_as_uint(f);
    unsigned int r = (u + 0x7FFFu + ((u >> 16) & 1u)) >> 16;
    return (ushort_t)r;
}

// ---------------- embedding
__global__ void k_embed(const float* __restrict__ x, const float* __restrict__ W,
                        const float* __restrict__ bias, float* __restrict__ h) {
    int i = blockIdx.x * 256 + threadIdx.x;
    if (i >= BL * DM) return;
    int d = i % DM, r = i / DM;
    h[i] = x[r * 2 + 0] * W[d * 2 + 0] + x[r * 2 + 1] * W[d * 2 + 1] + bias[d];
}

// ---------------- fp32 -> bf16 bulk convert
__global__ void k_cvt(const float* __restrict__ in, ushort_t* __restrict__ out, int n4) {
    int i = blockIdx.x * 256 + threadIdx.x;
    if (i >= n4) return;
    float4 v = *(const float4*)(in + (size_t)i * 4);
    ushort_t o[4] = {f2b(v.x), f2b(v.y), f2b(v.z), f2b(v.w)};
    *(uint2*)(out + (size_t)i * 4) = *(uint2*)o;
}

// ---------------- rmsnorm over rows of 512; BF16OUT selects output dtype
template <int BF16OUT>
__global__ __launch_bounds__(256) void k_rmsnorm(const float* __restrict__ in,
                                                 const float* __restrict__ w,
                                                 void* __restrict__ outp) {
    int m = blockIdx.x;
    int tid = threadIdx.x;
    const float* row = in + (size_t)m * DM;
    float2 v = *(const float2*)(row + tid * 2);
    float ss = v.x * v.x + v.y * v.y;
    #pragma unroll
    for (int o = 32; o > 0; o >>= 1) ss += __shfl_down(ss, o, 64);
    __shared__ float red[4];
    int wid = tid >> 6;
    if ((tid & 63) == 0) red[wid] = ss;
    __syncthreads();
    float tot = red[0] + red[1] + red[2] + red[3];
    float rs = rsqrtf(tot * (1.f / DM) + 1e-5f);
    float2 wv = *(const float2*)(w + tid * 2);
    float ox = v.x * rs * wv.x;
    float oy = v.y * rs * wv.y;
    if (BF16OUT) {
        ushort_t o[2] = {f2b(ox), f2b(oy)};
        *(unsigned int*)((ushort_t*)outp + (size_t)m * DM + tid * 2) = *(unsigned int*)o;
    } else {
        *(float2*)((float*)outp + (size_t)m * DM + tid * 2) = make_float2(ox, oy);
    }
}

// ---------------- bf16 MFMA GEMM: C[m,n] = (ADD?Res:0) + sum_k A[m,k]*W[n,k]
template <int ADDRES>
__global__ __launch_bounds__(256) void k_bgemm(const ushort_t* __restrict__ A,
                                               const ushort_t* __restrict__ W,
                                               const float* __restrict__ Res,
                                               float* __restrict__ C,
                                               int M, int N, int K, int lda, int ldc) {
    __shared__ ushort_t As[128 * LDSK];
    __shared__ ushort_t Bs[128 * LDSK];
    int tid = threadIdx.x;
    int bm = blockIdx.y * 128, bn = blockIdx.x * 128;
    int wave = tid >> 6, lane = tid & 63;
    int wr = wave >> 1, wc = wave & 1;       // 2x2 wave grid, 64x64 each
    int lr = lane & 15, lk = (lane >> 4) * 8;
    int srow = tid >> 2;                     // staging: 0..63
    int skb = (tid & 3) * 8;                 // k-chunk 0,8,16,24
    f32x4 acc[4][4];
    #pragma unroll
    for (int i = 0; i < 4; ++i)
        #pragma unroll
        for (int j = 0; j < 4; ++j) acc[i][j] = (f32x4){0.f, 0.f, 0.f, 0.f};

    for (int k0 = 0; k0 < K; k0 += 32) {
        uint4 a0 = *(const uint4*)(A + (size_t)(bm + srow) * lda + k0 + skb);
        uint4 a1 = *(const uint4*)(A + (size_t)(bm + 64 + srow) * lda + k0 + skb);
        uint4 b0 = *(const uint4*)(W + (size_t)(bn + srow) * K + k0 + skb);
        uint4 b1 = *(const uint4*)(W + (size_t)(bn + 64 + srow) * K + k0 + skb);
        __syncthreads();
        *(uint4*)(As + srow * LDSK + skb) = a0;
        *(uint4*)(As + (64 + srow) * LDSK + skb) = a1;
        *(uint4*)(Bs + srow * LDSK + skb) = b0;
        *(uint4*)(Bs + (64 + srow) * LDSK + skb) = b1;
        __syncthreads();
        bf16x8 af[4], bfr[4];
        #pragma unroll
        for (int i = 0; i < 4; ++i)
            af[i] = *(const bf16x8*)(As + (wr * 64 + i * 16 + lr) * LDSK + lk);
        #pragma unroll
        for (int j = 0; j < 4; ++j)
            bfr[j] = *(const bf16x8*)(Bs + (wc * 64 + j * 16 + lr) * LDSK + lk);
        #pragma unroll
        for (int i = 0; i < 4; ++i)
            #pragma unroll
            for (int j = 0; j < 4; ++j)
                acc[i][j] = __builtin_amdgcn_mfma_f32_16x16x32_bf16(af[i], bfr[j], acc[i][j], 0, 0, 0);
    }
    int crow0 = bm + wr * 64 + (lane >> 4) * 4;
    int ccol0 = bn + wc * 64 + lr;
    #pragma unroll
    for (int i = 0; i < 4; ++i)
        #pragma unroll
        for (int j = 0; j < 4; ++j)
            #pragma unroll
            for (int r = 0; r < 4; ++r) {
                size_t off = (size_t)(crow0 + i * 16 + r) * ldc + ccol0 + j * 16;
                float v = acc[i][j][r];
                if (ADDRES) v += Res[off];
                C[off] = v;
            }
}

// ---------------- x_proj split-K: Pp[s][m][n] = sum_{k in slice s} u[m,k]*W[n,k]
// grid (XKS, BL/64); 64x64 tile per block over a K=64 slice.
__global__ __launch_bounds__(256) void k_xproj(const float* __restrict__ A,
                                               const float* __restrict__ W,
                                               float* __restrict__ Pp) {
    __shared__ float As[64][XPAD];
    __shared__ float Ws[64][XPAD];
    int tid = threadIdx.x;
    int k0 = blockIdx.x * 64;
    int bm = blockIdx.y * 64;
    int r = tid >> 2;            // 0..63
    int kc = (tid & 3) * 16;     // 0,16,32,48
    const float4* ap = (const float4*)(A + (size_t)(bm + r) * ED + k0 + kc);
    const float4* wp = (const float4*)(W + (size_t)r * ED + k0 + kc);
    #pragma unroll
    for (int i = 0; i < 4; ++i) {
        float4 av = ap[i];
        float4 wv = wp[i];
        As[kc + i * 4 + 0][r] = av.x; As[kc + i * 4 + 1][r] = av.y;
        As[kc + i * 4 + 2][r] = av.z; As[kc + i * 4 + 3][r] = av.w;
        Ws[kc + i * 4 + 0][r] = wv.x; Ws[kc + i * 4 + 1][r] = wv.y;
        Ws[kc + i * 4 + 2][r] = wv.z; Ws[kc + i * 4 + 3][r] = wv.w;
    }
    __syncthreads();
    int tm = (tid >> 4) * 4;
    int tn = (tid & 15) * 4;
    float acc[4][4] = {};
    #pragma unroll 4
    for (int k = 0; k < 64; ++k) {
        float4 a = *(const float4*)&As[k][tm];
        float4 b = *(const float4*)&Ws[k][tn];
        acc[0][0] += a.x * b.x; acc[0][1] += a.x * b.y; acc[0][2] += a.x * b.z; acc[0][3] += a.x * b.w;
        acc[1][0] += a.y * b.x; acc[1][1] += a.y * b.y; acc[1][2] += a.y * b.z; acc[1][3] += a.y * b.w;
        acc[2][0] += a.z * b.x; acc[2][1] += a.z * b.y; acc[2][2] += a.z * b.z; acc[2][3] += a.z * b.w;
        acc[3][0] += a.w * b.x; acc[3][1] += a.w * b.y; acc[3][2] += a.w * b.z; acc[3][3] += a.w * b.w;
    }
    float* pp = Pp + (size_t)blockIdx.x * BL * XDBC;
    #pragma unroll
    for (int i = 0; i < 4; ++i)
        *(float4*)(pp + (size_t)(bm + tm + i) * XDBC + tn) =
            make_float4(acc[i][0], acc[i][1], acc[i][2], acc[i][3]);
}

// reduce 16 K-slice partials -> xdb
__global__ void k_xred(const float* __restrict__ Pp, float* __restrict__ xdb) {
    int i = blockIdx.x * 256 + threadIdx.x;   // float4 index, 65536 total
    float4 s = make_float4(0.f, 0.f, 0.f, 0.f);
    #pragma unroll
    for (int sl = 0; sl < XKS; ++sl) {
        float4 v = *(const float4*)(Pp + (size_t)sl * BL * XDBC + (size_t)i * 4);
        s.x += v.x; s.y += v.y; s.z += v.z; s.w += v.w;
    }
    *(float4*)(xdb + (size_t)i * 4) = s;
}

// ---------------- causal depthwise conv (k=4) + bias + silu
__global__ void k_conv(const float* __restrict__ xz, const float* __restrict__ cw,
                       const float* __restrict__ cb, float* __restrict__ u) {
    int i = blockIdx.x * 256 + threadIdx.x;
    if (i >= BL * ED) return;
    int e = i % ED;
    int t = (i / ED) % LL;
    int b = i / (ED * LL);
    const float* col = xz + (size_t)b * LL * 2048 + e;
    float4 w4 = *(const float4*)(cw + e * 4);
    float acc = cb[e];
    if (t >= 3) acc += col[(size_t)(t - 3) * 2048] * w4.x;
    if (t >= 2) acc += col[(size_t)(t - 2) * 2048] * w4.y;
    if (t >= 1) acc += col[(size_t)(t - 1) * 2048] * w4.z;
    acc += col[(size_t)t * 2048] * w4.w;
    u[i] = silu_f(acc);
}

// ---------------- delta = softplus(dt @ dtW^T + dtb)
__global__ __launch_bounds__(256) void k_delta(const float* __restrict__ xdb,
                                               const float* __restrict__ dtW,
                                               const float* __restrict__ dtb,
                                               float* __restrict__ delta) {
    int m = blockIdx.x;
    int tid = threadIdx.x;
    __shared__ float dt[32];
    if (tid < 32) dt[tid] = xdb[(size_t)m * XDBC + tid];
    __syncthreads();
    for (int e = tid; e < ED; e += 256) {
        const float4* wp = (const float4*)(dtW + (size_t)e * 32);
        float acc = dtb[e];
        #pragma unroll
        for (int q = 0; q < 8; ++q) {
            float4 w = wp[q];
            acc += dt[q * 4 + 0] * w.x + dt[q * 4 + 1] * w.y +
                   dt[q * 4 + 2] * w.z + dt[q * 4 + 3] * w.w;
        }
        delta[(size_t)m * ED + e] = (acc > 20.f) ? acc : __logf(1.f + __expf(acc));
    }
}

// ================ chunked selective scan ================
__global__ __launch_bounds__(256) void k_scan1(const float* __restrict__ delta,
                                               const float* __restrict__ u,
                                               const float* __restrict__ xdb,
                                               const float* __restrict__ A_log,
                                               float* __restrict__ P,
                                               float* __restrict__ S) {
    int tid = threadIdx.x;
    int e = ((blockIdx.x & 3) << 8) + tid;
    int c = (blockIdx.x >> 2) & (NC - 1);
    int b = blockIdx.x >> 7;
    float Ac[16];
    const float4* ap = (const float4*)(A_log + (size_t)e * NST);
    #pragma unroll
    for (int q = 0; q < 4; ++q) {
        float4 a = ap[q];
        Ac[q * 4 + 0] = -__expf(a.x); Ac[q * 4 + 1] = -__expf(a.y);
        Ac[q * 4 + 2] = -__expf(a.z); Ac[q * 4 + 3] = -__expf(a.w);
    }
    float h[16] = {};
    float s = 0.f;
    const float* dp = delta + ((size_t)b * LL + c * CS) * ED + e;
    const float* up = u + ((size_t)b * LL + c * CS) * ED + e;
    const float* xp = xdb + ((size_t)b * LL + c * CS) * XDBC;
    for (int tt = 0; tt < CS; ++tt) {
        float dv = dp[(size_t)tt * ED];
        float uv = up[(size_t)tt * ED];
        s += dv;
        float du = dv * uv;
        const float4* bp = (const float4*)(xp + tt * XDBC + DTR);
        #pragma unroll
        for (int q = 0; q < 4; ++q) {
            float4 bv = bp[q];
            h[q * 4 + 0] = __expf(dv * Ac[q * 4 + 0]) * h[q * 4 + 0] + du * bv.x;
            h[q * 4 + 1] = __expf(dv * Ac[q * 4 + 1]) * h[q * 4 + 1] + du * bv.y;
            h[q * 4 + 2] = __expf(dv * Ac[q * 4 + 2]) * h[q * 4 + 2] + du * bv.z;
            h[q * 4 + 3] = __expf(dv * Ac[q * 4 + 3]) * h[q * 4 + 3] + du * bv.w;
        }
    }
    float4* pp = (float4*)(P + ((size_t)(b * NC + c) * ED + e) * NST);
    pp[0] = make_float4(h[0], h[1], h[2], h[3]);
    pp[1] = make_float4(h[4], h[5], h[6], h[7]);
    pp[2] = make_float4(h[8], h[9], h[10], h[11]);
    pp[3] = make_float4(h[12], h[13], h[14], h[15]);
    S[(size_t)(b * NC + c) * ED + e] = s;
}

__global__ __launch_bounds__(256) void k_scan2(float* __restrict__ P,
                                               const float* __restrict__ S,
                                               const float* __restrict__ A_log) {
    int i = blockIdx.x * 256 + threadIdx.x;
    int n = i & 15;
    int e = (i >> 4) & (ED - 1);
    int b = i >> 14;
    float Ac = -__expf(A_log[(size_t)e * NST + n]);
    float hin = 0.f;
    for (int c = 0; c < NC; ++c) {
        size_t base = (size_t)(b * NC + c) * ED + e;
        float p = P[base * NST + n];
        float s = S[base];
        P[base * NST + n] = hin;
        hin = __expf(Ac * s) * hin + p;
    }
}

// Pass 3: re-scan with correct h_in; y = sum_n h*C + D*u, fused silu(z) gate;
// emits bf16 yb for the out_proj MFMA GEMM.
__global__ __launch_bounds__(256) void k_scan3(const float* __restrict__ dy,
                                               const float* __restrict__ u,
                                               const float* __restrict__ xdb,
                                               const float* __restrict__ xz,
                                               const float* __restrict__ A_log,
                                               const float* __restrict__ Dskip,
                                               const float* __restrict__ P,
                                               ushort_t* __restrict__ yb) {
    int tid = threadIdx.x;
    int e = ((blockIdx.x & 3) << 8) + tid;
    int c = (blockIdx.x >> 2) & (NC - 1);
    int b = blockIdx.x >> 7;
    float Ac[16], h[16];
    const float4* ap = (const float4*)(A_log + (size_t)e * NST);
    #pragma unroll
    for (int q = 0; q < 4; ++q) {
        float4 a = ap[q];
        Ac[q * 4 + 0] = -__expf(a.x); Ac[q * 4 + 1] = -__expf(a.y);
        Ac[q * 4 + 2] = -__expf(a.z); Ac[q * 4 + 3] = -__expf(a.w);
    }
    const float4* pp = (const float4*)(P + ((size_t)(b * NC + c) * ED + e) * NST);
    #pragma unroll
    for (int q = 0; q < 4; ++q) {
        float4 hv = pp[q];
        h[q * 4 + 0] = hv.x; h[q * 4 + 1] = hv.y;
        h[q * 4 + 2] = hv.z; h[q * 4 + 3] = hv.w;
    }
    float Dk = Dskip[e];
    const float* dp = dy + ((size_t)b * LL + c * CS) * ED + e;
    const float* up = u + ((size_t)b * LL + c * CS) * ED + e;
    const float* xp = xdb + ((size_t)b * LL + c * CS) * XDBC;
    const float* zp = xz + ((size_t)b * LL + c * CS) * 2048 + 1024 + e;
    ushort_t* yp = yb + ((size_t)b * LL + c * CS) * ED + e;
    for (int tt = 0; tt < CS; ++tt) {
        float dv = dp[(size_t)tt * ED];
        float uv = up[(size_t)tt * ED];
        float zv = zp[(size_t)tt * 2048];
        float du = dv * uv;
        const float4* bp = (const float4*)(xp + tt * XDBC + DTR);
        const float4* cp = (const float4*)(xp + tt * XDBC + DTR + NST);
        float y = 0.f;
        #pragma unroll
        for (int q = 0; q < 4; ++q) {
            float4 bv = bp[q];
            float4 cv = cp[q];
            h[q * 4 + 0] = __expf(dv * Ac[q * 4 + 0]) * h[q * 4 + 0] + du * bv.x;
            h[q * 4 + 1] = __expf(dv * Ac[q * 4 + 1]) * h[q * 4 + 1] + du * bv.y;
            h[q * 4 + 2] = __expf(dv * Ac[q * 4 + 2]) * h[q * 4 + 2] + du * bv.z;
            h[q * 4 + 3] = __expf(dv * Ac[q * 4 + 3]) * h[q * 4 + 3] + du * bv.w;
            y += h[q * 4 + 0] * cv.x + h[q * 4 + 1] * cv.y +
                 h[q * 4 + 2] * cv.z + h[q * 4 + 3] * cv.w;
        }
        yp[(size_t)tt * ED] = f2b((y + Dk * uv) * silu_f(zv));
    }
}

extern "C" void kernel_launch(void* const* d_in, const int* in_sizes, int n_in,
                              void* d_out, int out_size, void* d_ws, size_t ws_size,
                              hipStream_t stream) {
    const float* x     = (const float*)d_in[0];
    const float* embW  = (const float*)d_in[1];
    const float* embB  = (const float*)d_in[2];
    const float* normw = (const float*)d_in[3];
    const float* ipW   = (const float*)d_in[4];
    const float* cW    = (const float*)d_in[5];
    const float* cb    = (const float*)d_in[6];
    const float* xpW   = (const float*)d_in[7];
    const float* dtW   = (const float*)d_in[8];
    const float* dtb   = (const float*)d_in[9];
    const float* Alog  = (const float*)d_in[10];
    const float* Dsk   = (const float*)d_in[11];
    const float* opW   = (const float*)d_in[12];
    const float* normfw= (const float*)d_in[13];
    float* out = (float*)d_out;

    // ws (floats): h 2M | xz 8M | u 4M | xdb 256K | dy 4M | S 128K, then
    // ushorts: wip/wop 2.5M | yb 4M. Pp (x_proj partials, 4M floats) ALIASES
    // dy: Pp live only between k_xproj and k_xred; dy written after by k_delta.
    float* ws  = (float*)d_ws;
    float* h   = ws;
    float* xz  = h + (size_t)BL * DM;
    float* u   = xz + (size_t)BL * 2 * ED;
    float* xdb = u + (size_t)BL * ED;
    float* dy  = xdb + (size_t)BL * XDBC;
    float* S   = dy + (size_t)BL * ED;
    ushort_t* wip = (ushort_t*)(S + (size_t)BB * NC * ED);  // 2*ED*DM bf16
    ushort_t* wop = wip + (size_t)2 * ED * DM;              // DM*ED bf16
    ushort_t* yb  = wop + (size_t)DM * ED;                  // BL*ED bf16
    float* Pp     = dy;                // split-K partials (aliases dy)
    ushort_t* hnb = (ushort_t*)d_out;  // bf16 rmsnorm scratch (d_out reuse)
    float* P      = out;               // chunk-state buffer (d_out reuse)

    k_embed<<<(BL * DM + 255) / 256, 256, 0, stream>>>(x, embW, embB, h);
    for (int l = 0; l < 2; ++l) {
        k_cvt<<<(2 * ED * DM / 4 + 255) / 256, 256, 0, stream>>>(
            ipW + (size_t)l * 2 * ED * DM, wip, 2 * ED * DM / 4);
        k_cvt<<<(DM * ED / 4 + 255) / 256, 256, 0, stream>>>(
            opW + (size_t)l * DM * ED, wop, DM * ED / 4);
        k_rmsnorm<1><<<BL, 256, 0, stream>>>(h, normw + (size_t)l * DM, hnb);
        k_bgemm<0><<<dim3(2 * ED / 128, BL / 128), 256, 0, stream>>>(
            hnb, wip, nullptr, xz, BL, 2 * ED, DM, DM, 2 * ED);
        k_conv<<<(BL * ED + 255) / 256, 256, 0, stream>>>(
            xz, cW + (size_t)l * ED * 4, cb + (size_t)l * ED, u);
        k_xproj<<<dim3(XKS, BL / 64), 256, 0, stream>>>(
            u, xpW + (size_t)l * XDBC * ED, Pp);
        k_xred<<<BL * XDBC / 4 / 256, 256, 0, stream>>>(Pp, xdb);
        k_delta<<<BL, 256, 0, stream>>>(
            xdb, dtW + (size_t)l * ED * DTR, dtb + (size_t)l * ED, dy);
        const float* Al = Alog + (size_t)l * ED * NST;
        k_scan1<<<BB * NC * (ED / 256), 256, 0, stream>>>(dy, u, xdb, Al, P, S);
        k_scan2<<<BB * ED * NST / 256, 256, 0, stream>>>(P, S, Al);
        k_scan3<<<BB * NC * (ED / 256), 256, 0, stream>>>(
            dy, u, xdb, xz, Al, Dsk + (size_t)l * ED, P, yb);
        k_bgemm<1><<<dim3(DM / 128, BL / 128), 256, 0, stream>>>(
            yb, wop, h, h, BL, DM, ED, ED, DM);
    }
    k_rmsnorm<0><<<BL, 256, 0, stream>>>(h, normfw, out);
}

// Round 9
// 317.030 us; speedup vs baseline: 5.2803x; 1.2880x over previous
//
#include <hip/hip_runtime.h>
#include <math.h>
#include <stddef.h>

#define BB 4
#define LL 1024
#define DM 512
#define ED 1024
#define NST 16
#define DTR 32
#define XDBC 64
#define BL (BB*LL)   // 4096
#define CS 32        // scan chunk length
#define NC 32        // chunks per sequence (LL/CS)
#define LDSK 40      // padded LDS k-stride (ushorts) for bf16 GEMM
#define XKS 16       // x_proj K-slices
#define XPAD 68      // x_proj LDS stride (floats)
#define DPAD 132     // k_delta LDS stride (floats)

typedef __attribute__((ext_vector_type(8))) short bf16x8;
typedef __attribute__((ext_vector_type(4))) float f32x4;
typedef unsigned short ushort_t;

__device__ __forceinline__ float silu_f(float x) { return x / (1.f + __expf(-x)); }

// fp32 -> bf16 round-to-nearest-even
__device__ __forceinline__ ushort_t f2b(float f) {
    unsigned int u = __float_as_uint(f);
    unsigned int r = (u + 0x7FFFu + ((u >> 16) & 1u)) >> 16;
    return (ushort_t)r;
}

// ---------------- embedding
__global__ void k_embed(const float* __restrict__ x, const float* __restrict__ W,
                        const float* __restrict__ bias, float* __restrict__ h) {
    int i = blockIdx.x * 256 + threadIdx.x;
    if (i >= BL * DM) return;
    int d = i % DM, r = i / DM;
    h[i] = x[r * 2 + 0] * W[d * 2 + 0] + x[r * 2 + 1] * W[d * 2 + 1] + bias[d];
}

// ---------------- fp32 -> bf16 bulk convert
__global__ void k_cvt(const float* __restrict__ in, ushort_t* __restrict__ out, int n4) {
    int i = blockIdx.x * 256 + threadIdx.x;
    if (i >= n4) return;
    float4 v = *(const float4*)(in + (size_t)i * 4);
    ushort_t o[4] = {f2b(v.x), f2b(v.y), f2b(v.z), f2b(v.w)};
    *(uint2*)(out + (size_t)i * 4) = *(uint2*)o;
}

// ---------------- rmsnorm over rows of 512; BF16OUT selects output dtype
template <int BF16OUT>
__global__ __launch_bounds__(256) void k_rmsnorm(const float* __restrict__ in,
                                                 const float* __restrict__ w,
                                                 void* __restrict__ outp) {
    int m = blockIdx.x;
    int tid = threadIdx.x;
    const float* row = in + (size_t)m * DM;
    float2 v = *(const float2*)(row + tid * 2);
    float ss = v.x * v.x + v.y * v.y;
    #pragma unroll
    for (int o = 32; o > 0; o >>= 1) ss += __shfl_down(ss, o, 64);
    __shared__ float red[4];
    int wid = tid >> 6;
    if ((tid & 63) == 0) red[wid] = ss;
    __syncthreads();
    float tot = red[0] + red[1] + red[2] + red[3];
    float rs = rsqrtf(tot * (1.f / DM) + 1e-5f);
    float2 wv = *(const float2*)(w + tid * 2);
    float ox = v.x * rs * wv.x;
    float oy = v.y * rs * wv.y;
    if (BF16OUT) {
        ushort_t o[2] = {f2b(ox), f2b(oy)};
        *(unsigned int*)((ushort_t*)outp + (size_t)m * DM + tid * 2) = *(unsigned int*)o;
    } else {
        *(float2*)((float*)outp + (size_t)m * DM + tid * 2) = make_float2(ox, oy);
    }
}

// ---------------- bf16 MFMA GEMM: C[m,n] = (ADD?Res:0) + sum_k A[m,k]*W[n,k]
template <int ADDRES>
__global__ __launch_bounds__(256) void k_bgemm(const ushort_t* __restrict__ A,
                                               const ushort_t* __restrict__ W,
                                               const float* __restrict__ Res,
                                               float* __restrict__ C,
                                               int M, int N, int K, int lda, int ldc) {
    __shared__ ushort_t As[128 * LDSK];
    __shared__ ushort_t Bs[128 * LDSK];
    int tid = threadIdx.x;
    int bm = blockIdx.y * 128, bn = blockIdx.x * 128;
    int wave = tid >> 6, lane = tid & 63;
    int wr = wave >> 1, wc = wave & 1;       // 2x2 wave grid, 64x64 each
    int lr = lane & 15, lk = (lane >> 4) * 8;
    int srow = tid >> 2;                     // staging: 0..63
    int skb = (tid & 3) * 8;                 // k-chunk 0,8,16,24
    f32x4 acc[4][4];
    #pragma unroll
    for (int i = 0; i < 4; ++i)
        #pragma unroll
        for (int j = 0; j < 4; ++j) acc[i][j] = (f32x4){0.f, 0.f, 0.f, 0.f};

    for (int k0 = 0; k0 < K; k0 += 32) {
        uint4 a0 = *(const uint4*)(A + (size_t)(bm + srow) * lda + k0 + skb);
        uint4 a1 = *(const uint4*)(A + (size_t)(bm + 64 + srow) * lda + k0 + skb);
        uint4 b0 = *(const uint4*)(W + (size_t)(bn + srow) * K + k0 + skb);
        uint4 b1 = *(const uint4*)(W + (size_t)(bn + 64 + srow) * K + k0 + skb);
        __syncthreads();
        *(uint4*)(As + srow * LDSK + skb) = a0;
        *(uint4*)(As + (64 + srow) * LDSK + skb) = a1;
        *(uint4*)(Bs + srow * LDSK + skb) = b0;
        *(uint4*)(Bs + (64 + srow) * LDSK + skb) = b1;
        __syncthreads();
        bf16x8 af[4], bfr[4];
        #pragma unroll
        for (int i = 0; i < 4; ++i)
            af[i] = *(const bf16x8*)(As + (wr * 64 + i * 16 + lr) * LDSK + lk);
        #pragma unroll
        for (int j = 0; j < 4; ++j)
            bfr[j] = *(const bf16x8*)(Bs + (wc * 64 + j * 16 + lr) * LDSK + lk);
        #pragma unroll
        for (int i = 0; i < 4; ++i)
            #pragma unroll
            for (int j = 0; j < 4; ++j)
                acc[i][j] = __builtin_amdgcn_mfma_f32_16x16x32_bf16(af[i], bfr[j], acc[i][j], 0, 0, 0);
    }
    int crow0 = bm + wr * 64 + (lane >> 4) * 4;
    int ccol0 = bn + wc * 64 + lr;
    #pragma unroll
    for (int i = 0; i < 4; ++i)
        #pragma unroll
        for (int j = 0; j < 4; ++j)
            #pragma unroll
            for (int r = 0; r < 4; ++r) {
                size_t off = (size_t)(crow0 + i * 16 + r) * ldc + ccol0 + j * 16;
                float v = acc[i][j][r];
                if (ADDRES) v += Res[off];
                C[off] = v;
            }
}

// ---------------- x_proj split-K
__global__ __launch_bounds__(256) void k_xproj(const float* __restrict__ A,
                                               const float* __restrict__ W,
                                               float* __restrict__ Pp) {
    __shared__ float As[64][XPAD];
    __shared__ float Ws[64][XPAD];
    int tid = threadIdx.x;
    int k0 = blockIdx.x * 64;
    int bm = blockIdx.y * 64;
    int r = tid >> 2;            // 0..63
    int kc = (tid & 3) * 16;     // 0,16,32,48
    const float4* ap = (const float4*)(A + (size_t)(bm + r) * ED + k0 + kc);
    const float4* wp = (const float4*)(W + (size_t)r * ED + k0 + kc);
    #pragma unroll
    for (int i = 0; i < 4; ++i) {
        float4 av = ap[i];
        float4 wv = wp[i];
        As[kc + i * 4 + 0][r] = av.x; As[kc + i * 4 + 1][r] = av.y;
        As[kc + i * 4 + 2][r] = av.z; As[kc + i * 4 + 3][r] = av.w;
        Ws[kc + i * 4 + 0][r] = wv.x; Ws[kc + i * 4 + 1][r] = wv.y;
        Ws[kc + i * 4 + 2][r] = wv.z; Ws[kc + i * 4 + 3][r] = wv.w;
    }
    __syncthreads();
    int tm = (tid >> 4) * 4;
    int tn = (tid & 15) * 4;
    float acc[4][4] = {};
    #pragma unroll 4
    for (int k = 0; k < 64; ++k) {
        float4 a = *(const float4*)&As[k][tm];
        float4 b = *(const float4*)&Ws[k][tn];
        acc[0][0] += a.x * b.x; acc[0][1] += a.x * b.y; acc[0][2] += a.x * b.z; acc[0][3] += a.x * b.w;
        acc[1][0] += a.y * b.x; acc[1][1] += a.y * b.y; acc[1][2] += a.y * b.z; acc[1][3] += a.y * b.w;
        acc[2][0] += a.z * b.x; acc[2][1] += a.z * b.y; acc[2][2] += a.z * b.z; acc[2][3] += a.z * b.w;
        acc[3][0] += a.w * b.x; acc[3][1] += a.w * b.y; acc[3][2] += a.w * b.z; acc[3][3] += a.w * b.w;
    }
    float* pp = Pp + (size_t)blockIdx.x * BL * XDBC;
    #pragma unroll
    for (int i = 0; i < 4; ++i)
        *(float4*)(pp + (size_t)(bm + tm + i) * XDBC + tn) =
            make_float4(acc[i][0], acc[i][1], acc[i][2], acc[i][3]);
}

// reduce 16 K-slice partials -> xdb
__global__ void k_xred(const float* __restrict__ Pp, float* __restrict__ xdb) {
    int i = blockIdx.x * 256 + threadIdx.x;
    float4 s = make_float4(0.f, 0.f, 0.f, 0.f);
    #pragma unroll
    for (int sl = 0; sl < XKS; ++sl) {
        float4 v = *(const float4*)(Pp + (size_t)sl * BL * XDBC + (size_t)i * 4);
        s.x += v.x; s.y += v.y; s.z += v.z; s.w += v.w;
    }
    *(float4*)(xdb + (size_t)i * 4) = s;
}

// ---------------- causal depthwise conv (k=4) + bias + silu
__global__ void k_conv(const float* __restrict__ xz, const float* __restrict__ cw,
                       const float* __restrict__ cb, float* __restrict__ u) {
    int i = blockIdx.x * 256 + threadIdx.x;
    if (i >= BL * ED) return;
    int e = i % ED;
    int t = (i / ED) % LL;
    int b = i / (ED * LL);
    const float* col = xz + (size_t)b * LL * 2048 + e;
    float4 w4 = *(const float4*)(cw + e * 4);
    float acc = cb[e];
    if (t >= 3) acc += col[(size_t)(t - 3) * 2048] * w4.x;
    if (t >= 2) acc += col[(size_t)(t - 2) * 2048] * w4.y;
    if (t >= 1) acc += col[(size_t)(t - 1) * 2048] * w4.z;
    acc += col[(size_t)t * 2048] * w4.w;
    u[i] = silu_f(acc);
}

// ---------------- delta = softplus(dt @ dtW^T + dtb), tiled with LDS staging
// M=BL, N=ED, K=32. Grid (ED/128, BL/128), 256 thr, 8x8 outputs/thread.
__global__ __launch_bounds__(256) void k_delta(const float* __restrict__ xdb,
                                               const float* __restrict__ dtW,
                                               const float* __restrict__ dtb,
                                               float* __restrict__ delta) {
    __shared__ float Dt[32][DPAD];   // [k][m-row]
    __shared__ float Wt[32][DPAD];   // [k][e-col]
    int tid = threadIdx.x;
    int bm = blockIdx.y * 128;
    int bn = blockIdx.x * 128;
    int r = tid >> 1;               // 0..127
    int hh = (tid & 1) * 16;        // 0 or 16
    const float4* dp = (const float4*)(xdb + (size_t)(bm + r) * XDBC + hh);
    const float4* wp = (const float4*)(dtW + (size_t)(bn + r) * 32 + hh);
    #pragma unroll
    for (int i = 0; i < 4; ++i) {
        float4 v = dp[i];
        Dt[hh + i * 4 + 0][r] = v.x; Dt[hh + i * 4 + 1][r] = v.y;
        Dt[hh + i * 4 + 2][r] = v.z; Dt[hh + i * 4 + 3][r] = v.w;
        float4 w = wp[i];
        Wt[hh + i * 4 + 0][r] = w.x; Wt[hh + i * 4 + 1][r] = w.y;
        Wt[hh + i * 4 + 2][r] = w.z; Wt[hh + i * 4 + 3][r] = w.w;
    }
    __syncthreads();
    int tm = (tid >> 4) * 8;
    int tn = (tid & 15) * 8;
    float acc[8][8] = {};
    #pragma unroll 8
    for (int k = 0; k < 32; ++k) {
        float4 a0 = *(const float4*)&Dt[k][tm];
        float4 a1 = *(const float4*)&Dt[k][tm + 4];
        float4 b0 = *(const float4*)&Wt[k][tn];
        float4 b1 = *(const float4*)&Wt[k][tn + 4];
        float a[8] = {a0.x, a0.y, a0.z, a0.w, a1.x, a1.y, a1.z, a1.w};
        float b[8] = {b0.x, b0.y, b0.z, b0.w, b1.x, b1.y, b1.z, b1.w};
        #pragma unroll
        for (int i = 0; i < 8; ++i)
            #pragma unroll
            for (int j = 0; j < 8; ++j) acc[i][j] += a[i] * b[j];
    }
    float4 t0 = *(const float4*)(dtb + bn + tn);
    float4 t1 = *(const float4*)(dtb + bn + tn + 4);
    float bias[8] = {t0.x, t0.y, t0.z, t0.w, t1.x, t1.y, t1.z, t1.w};
    #pragma unroll
    for (int i = 0; i < 8; ++i) {
        float o[8];
        #pragma unroll
        for (int j = 0; j < 8; ++j) {
            float v = acc[i][j] + bias[j];
            o[j] = (v > 20.f) ? v : __logf(1.f + __expf(v));
        }
        size_t off = (size_t)(bm + tm + i) * ED + bn + tn;
        *(float4*)(delta + off) = make_float4(o[0], o[1], o[2], o[3]);
        *(float4*)(delta + off + 4) = make_float4(o[4], o[5], o[6], o[7]);
    }
}

// ================ chunked selective scan ================
__global__ __launch_bounds__(256) void k_scan1(const float* __restrict__ delta,
                                               const float* __restrict__ u,
                                               const float* __restrict__ xdb,
                                               const float* __restrict__ A_log,
                                               float* __restrict__ P,
                                               float* __restrict__ S) {
    int tid = threadIdx.x;
    int e = ((blockIdx.x & 3) << 8) + tid;
    int c = (blockIdx.x >> 2) & (NC - 1);
    int b = blockIdx.x >> 7;
    float Ac[16];
    const float4* ap = (const float4*)(A_log + (size_t)e * NST);
    #pragma unroll
    for (int q = 0; q < 4; ++q) {
        float4 a = ap[q];
        Ac[q * 4 + 0] = -__expf(a.x); Ac[q * 4 + 1] = -__expf(a.y);
        Ac[q * 4 + 2] = -__expf(a.z); Ac[q * 4 + 3] = -__expf(a.w);
    }
    float h[16] = {};
    float s = 0.f;
    const float* dp = delta + ((size_t)b * LL + c * CS) * ED + e;
    const float* up = u + ((size_t)b * LL + c * CS) * ED + e;
    const float* xp = xdb + ((size_t)b * LL + c * CS) * XDBC;
    for (int tt = 0; tt < CS; ++tt) {
        float dv = dp[(size_t)tt * ED];
        float uv = up[(size_t)tt * ED];
        s += dv;
        float du = dv * uv;
        const float4* bp = (const float4*)(xp + tt * XDBC + DTR);
        #pragma unroll
        for (int q = 0; q < 4; ++q) {
            float4 bv = bp[q];
            h[q * 4 + 0] = __expf(dv * Ac[q * 4 + 0]) * h[q * 4 + 0] + du * bv.x;
            h[q * 4 + 1] = __expf(dv * Ac[q * 4 + 1]) * h[q * 4 + 1] + du * bv.y;
            h[q * 4 + 2] = __expf(dv * Ac[q * 4 + 2]) * h[q * 4 + 2] + du * bv.z;
            h[q * 4 + 3] = __expf(dv * Ac[q * 4 + 3]) * h[q * 4 + 3] + du * bv.w;
        }
    }
    float4* pp = (float4*)(P + ((size_t)(b * NC + c) * ED + e) * NST);
    pp[0] = make_float4(h[0], h[1], h[2], h[3]);
    pp[1] = make_float4(h[4], h[5], h[6], h[7]);
    pp[2] = make_float4(h[8], h[9], h[10], h[11]);
    pp[3] = make_float4(h[12], h[13], h[14], h[15]);
    S[(size_t)(b * NC + c) * ED + e] = s;
}

__global__ __launch_bounds__(256) void k_scan2(float* __restrict__ P,
                                               const float* __restrict__ S,
                                               const float* __restrict__ A_log) {
    int i = blockIdx.x * 256 + threadIdx.x;
    int n = i & 15;
    int e = (i >> 4) & (ED - 1);
    int b = i >> 14;
    float Ac = -__expf(A_log[(size_t)e * NST + n]);
    float hin = 0.f;
    for (int c = 0; c < NC; ++c) {
        size_t base = (size_t)(b * NC + c) * ED + e;
        float p = P[base * NST + n];
        float s = S[base];
        P[base * NST + n] = hin;
        hin = __expf(Ac * s) * hin + p;
    }
}

// Pass 3: re-scan with correct h_in; fused silu(z) gate; emits bf16 yb.
__global__ __launch_bounds__(256) void k_scan3(const float* __restrict__ dy,
                                               const float* __restrict__ u,
                                               const float* __restrict__ xdb,
                                               const float* __restrict__ xz,
                                               const float* __restrict__ A_log,
                                               const float* __restrict__ Dskip,
                                               const float* __restrict__ P,
                                               ushort_t* __restrict__ yb) {
    int tid = threadIdx.x;
    int e = ((blockIdx.x & 3) << 8) + tid;
    int c = (blockIdx.x >> 2) & (NC - 1);
    int b = blockIdx.x >> 7;
    float Ac[16], h[16];
    const float4* ap = (const float4*)(A_log + (size_t)e * NST);
    #pragma unroll
    for (int q = 0; q < 4; ++q) {
        float4 a = ap[q];
        Ac[q * 4 + 0] = -__expf(a.x); Ac[q * 4 + 1] = -__expf(a.y);
        Ac[q * 4 + 2] = -__expf(a.z); Ac[q * 4 + 3] = -__expf(a.w);
    }
    const float4* pp = (const float4*)(P + ((size_t)(b * NC + c) * ED + e) * NST);
    #pragma unroll
    for (int q = 0; q < 4; ++q) {
        float4 hv = pp[q];
        h[q * 4 + 0] = hv.x; h[q * 4 + 1] = hv.y;
        h[q * 4 + 2] = hv.z; h[q * 4 + 3] = hv.w;
    }
    float Dk = Dskip[e];
    const float* dp = dy + ((size_t)b * LL + c * CS) * ED + e;
    const float* up = u + ((size_t)b * LL + c * CS) * ED + e;
    const float* xp = xdb + ((size_t)b * LL + c * CS) * XDBC;
    const float* zp = xz + ((size_t)b * LL + c * CS) * 2048 + 1024 + e;
    ushort_t* yp = yb + ((size_t)b * LL + c * CS) * ED + e;
    for (int tt = 0; tt < CS; ++tt) {
        float dv = dp[(size_t)tt * ED];
        float uv = up[(size_t)tt * ED];
        float zv = zp[(size_t)tt * 2048];
        float du = dv * uv;
        const float4* bp = (const float4*)(xp + tt * XDBC + DTR);
        const float4* cp = (const float4*)(xp + tt * XDBC + DTR + NST);
        float y = 0.f;
        #pragma unroll
        for (int q = 0; q < 4; ++q) {
            float4 bv = bp[q];
            float4 cv = cp[q];
            h[q * 4 + 0] = __expf(dv * Ac[q * 4 + 0]) * h[q * 4 + 0] + du * bv.x;
            h[q * 4 + 1] = __expf(dv * Ac[q * 4 + 1]) * h[q * 4 + 1] + du * bv.y;
            h[q * 4 + 2] = __expf(dv * Ac[q * 4 + 2]) * h[q * 4 + 2] + du * bv.z;
            h[q * 4 + 3] = __expf(dv * Ac[q * 4 + 3]) * h[q * 4 + 3] + du * bv.w;
            y += h[q * 4 + 0] * cv.x + h[q * 4 + 1] * cv.y +
                 h[q * 4 + 2] * cv.z + h[q * 4 + 3] * cv.w;
        }
        yp[(size_t)tt * ED] = f2b((y + Dk * uv) * silu_f(zv));
    }
}

extern "C" void kernel_launch(void* const* d_in, const int* in_sizes, int n_in,
                              void* d_out, int out_size, void* d_ws, size_t ws_size,
                              hipStream_t stream) {
    const float* x     = (const float*)d_in[0];
    const float* embW  = (const float*)d_in[1];
    const float* embB  = (const float*)d_in[2];
    const float* normw = (const float*)d_in[3];
    const float* ipW   = (const float*)d_in[4];
    const float* cW    = (const float*)d_in[5];
    const float* cb    = (const float*)d_in[6];
    const float* xpW   = (const float*)d_in[7];
    const float* dtW   = (const float*)d_in[8];
    const float* dtb   = (const float*)d_in[9];
    const float* Alog  = (const float*)d_in[10];
    const float* Dsk   = (const float*)d_in[11];
    const float* opW   = (const float*)d_in[12];
    const float* normfw= (const float*)d_in[13];
    float* out = (float*)d_out;

    float* ws  = (float*)d_ws;
    float* h   = ws;
    float* xz  = h + (size_t)BL * DM;
    float* u   = xz + (size_t)BL * 2 * ED;
    float* xdb = u + (size_t)BL * ED;
    float* dy  = xdb + (size_t)BL * XDBC;
    float* S   = dy + (size_t)BL * ED;
    ushort_t* wip = (ushort_t*)(S + (size_t)BB * NC * ED);  // 2*ED*DM bf16
    ushort_t* wop = wip + (size_t)2 * ED * DM;              // DM*ED bf16
    ushort_t* yb  = wop + (size_t)DM * ED;                  // BL*ED bf16
    float* Pp     = dy;                // split-K partials (aliases dy)
    ushort_t* hnb = (ushort_t*)d_out;  // bf16 rmsnorm scratch (d_out reuse)
    float* P      = out;               // chunk-state buffer (d_out reuse)

    k_embed<<<(BL * DM + 255) / 256, 256, 0, stream>>>(x, embW, embB, h);
    for (int l = 0; l < 2; ++l) {
        k_cvt<<<(2 * ED * DM / 4 + 255) / 256, 256, 0, stream>>>(
            ipW + (size_t)l * 2 * ED * DM, wip, 2 * ED * DM / 4);
        k_cvt<<<(DM * ED / 4 + 255) / 256, 256, 0, stream>>>(
            opW + (size_t)l * DM * ED, wop, DM * ED / 4);
        k_rmsnorm<1><<<BL, 256, 0, stream>>>(h, normw + (size_t)l * DM, hnb);
        k_bgemm<0><<<dim3(2 * ED / 128, BL / 128), 256, 0, stream>>>(
            hnb, wip, nullptr, xz, BL, 2 * ED, DM, DM, 2 * ED);
        k_conv<<<(BL * ED + 255) / 256, 256, 0, stream>>>(
            xz, cW + (size_t)l * ED * 4, cb + (size_t)l * ED, u);
        k_xproj<<<dim3(XKS, BL / 64), 256, 0, stream>>>(
            u, xpW + (size_t)l * XDBC * ED, Pp);
        k_xred<<<BL * XDBC / 4 / 256, 256, 0, stream>>>(Pp, xdb);
        k_delta<<<dim3(ED / 128, BL / 128), 256, 0, stream>>>(
            xdb, dtW + (size_t)l * ED * DTR, dtb + (size_t)l * ED, dy);
        const float* Al = Alog + (size_t)l * ED * NST;
        k_scan1<<<BB * NC * (ED / 256), 256, 0, stream>>>(dy, u, xdb, Al, P, S);
        k_scan2<<<BB * ED * NST / 256, 256, 0, stream>>>(P, S, Al);
        k_scan3<<<BB * NC * (ED / 256), 256, 0, stream>>>(
            dy, u, xdb, xz, Al, Dsk + (size_t)l * ED, P, yb);
        k_bgemm<1><<<dim3(DM / 128, BL / 128), 256, 0, stream>>>(
            yb, wop, h, h, BL, DM, ED, ED, DM);
    }
    k_rmsnorm<0><<<BL, 256, 0, stream>>>(h, normfw, out);
}